// Round 1
// baseline (9706.065 us; speedup 1.0000x reference)
//
#include <hip/hip_runtime.h>

#define T_STEPS 4096
#define BATCH   128
#define HID     256

__device__ __forceinline__ float fast_tanh(float z) {
    // tanh(z) = 1 - 2/(exp(2z)+1); exact saturation at +/-inf, ~1e-6 abs err
    float e = __expf(2.0f * z);
    return 1.0f - 2.0f / (e + 1.0f);
}

__global__ __launch_bounds__(512, 2)
void odenet_kernel(const float* __restrict__ x,
                   const float* __restrict__ W1, const float* __restrict__ b1,
                   const float* __restrict__ W2, const float* __restrict__ b2,
                   const float* __restrict__ W3, const float* __restrict__ b3,
                   float* __restrict__ out)
{
    const int b    = blockIdx.x;      // batch element
    const int t    = threadIdx.x;     // 0..511
    const int j    = t & 255;         // output column of W2
    const int half = t >> 8;          // which 128-row half of W2
    const int lane = t & 63;
    const int wid  = t >> 6;

    __shared__ float x_lds[T_STEPS];  // 16 KB: this batch's input column
    __shared__ float h1_lds[HID];     // 1 KB
    __shared__ float part[512];       // 2 KB: GEMV partials
    __shared__ float red[4];          // wave partial sums of layer-3 dot

    // stage x[:, b] into LDS (one-time)
    for (int n = t; n < T_STEPS; n += 512) x_lds[n] = x[n * BATCH + b];

    // W2 half-column in registers: rows half*128 .. half*128+127, column j.
    // MUST be fully unrolled so all indices are static (else scratch).
    float w2r[128];
    #pragma unroll
    for (int i = 0; i < 128; ++i) w2r[i] = W2[(half * 128 + i) * HID + j];

    const float w1a = W1[j];           // W1[0][j] (state weight)
    const float w1b = W1[HID + j];     // W1[1][j] (input weight)
    const float b1v = b1[j];
    const float b2v = b2[j];
    const float w3v = W3[j];
    const float b3v = b3[0];

    float y = 0.0f;
    __syncthreads();

    for (int n = 0; n < T_STEPS; ++n) {
        // ---- phase A: emit state, layer 1 ----
        if (t == 0) out[n * BATCH + b] = y;   // traj[n] = y_n (pre-update)
        if (t < 256) {
            float xt = x_lds[n];
            float h1 = fast_tanh(fmaf(y, w1a, fmaf(xt, w1b, b1v)));
            h1_lds[j] = h1;
        }
        __syncthreads();

        // ---- phase B: register GEMV partial (half-column dot) ----
        float a0 = 0.f, a1 = 0.f, a2 = 0.f, a3 = 0.f;
        const float4* h4 = (const float4*)(h1_lds) + half * 32;
        #pragma unroll
        for (int i = 0; i < 32; ++i) {
            float4 h = h4[i];   // uniform address across wave -> LDS broadcast
            a0 = fmaf(h.x, w2r[4 * i + 0], a0);
            a1 = fmaf(h.y, w2r[4 * i + 1], a1);
            a2 = fmaf(h.z, w2r[4 * i + 2], a2);
            a3 = fmaf(h.w, w2r[4 * i + 3], a3);
        }
        part[t] = (a0 + a1) + (a2 + a3);
        __syncthreads();

        // ---- phase C: combine halves, layer-2 tanh, layer-3 dot + reduce ----
        if (t < 256) {
            float q  = part[t] + part[t + 256] + b2v;
            float h2 = fast_tanh(q);
            float p  = h2 * w3v;
            #pragma unroll
            for (int m = 32; m >= 1; m >>= 1) p += __shfl_xor(p, m, 64);
            if (lane == 0) red[wid] = p;
        }
        __syncthreads();

        // all threads update y redundantly (identical fp ops -> identical y)
        y += (red[0] + red[1] + red[2] + red[3]) + b3v;
    }
}

extern "C" void kernel_launch(void* const* d_in, const int* in_sizes, int n_in,
                              void* d_out, int out_size, void* d_ws, size_t ws_size,
                              hipStream_t stream) {
    const float* x  = (const float*)d_in[0];
    const float* W1 = (const float*)d_in[1];
    const float* b1 = (const float*)d_in[2];
    const float* W2 = (const float*)d_in[3];
    const float* b2 = (const float*)d_in[4];
    const float* W3 = (const float*)d_in[5];
    const float* b3 = (const float*)d_in[6];
    float* out = (float*)d_out;

    odenet_kernel<<<dim3(BATCH), dim3(512), 0, stream>>>(x, W1, b1, W2, b2, W3, b3, out);
}

// Round 2
// 5289.249 us; speedup vs baseline: 1.8351x; 1.8351x over previous
//
#include <hip/hip_runtime.h>

#define T_STEPS 4096
#define BATCH   128
#define HID     256

__device__ __forceinline__ float fast_tanh(float z) {
    // tanh(z) = 1 - 2/(exp(2z)+1); exact saturation at +/-inf, ~1e-6 abs err
    float e = __expf(2.0f * z);
    return 1.0f - 2.0f / (e + 1.0f);
}

// repeat macro: forces 32 NAMED float4 locals (no indexable array -> no
// scratch demotion; round-1 showed VGPR=80, i.e. w2r[128] went to scratch
// and the kernel was L2-bandwidth-bound on its own spill traffic)
#define RPT32(M) M(0) M(1) M(2) M(3) M(4) M(5) M(6) M(7) \
                 M(8) M(9) M(10) M(11) M(12) M(13) M(14) M(15) \
                 M(16) M(17) M(18) M(19) M(20) M(21) M(22) M(23) \
                 M(24) M(25) M(26) M(27) M(28) M(29) M(30) M(31)

__global__ __launch_bounds__(512, 2)
void odenet_kernel(const float* __restrict__ x,
                   const float* __restrict__ W1, const float* __restrict__ b1,
                   const float* __restrict__ W2, const float* __restrict__ b2,
                   const float* __restrict__ W3, const float* __restrict__ b3,
                   float* __restrict__ out)
{
    const int b    = blockIdx.x;      // batch element
    const int t    = threadIdx.x;     // 0..511
    const int j    = t & 255;         // output column of W2
    const int half = t >> 8;          // which 128-row half of W2
    const int lane = t & 63;
    const int wid  = t >> 6;
    const int r0   = half * 128;      // first row of this thread's half-column

    __shared__ float x_lds[T_STEPS];  // 16 KB: this batch's input column
    __shared__ float h1_lds[HID];     // 1 KB
    __shared__ float part[512];       // 2 KB: GEMV partials
    __shared__ float red[4];          // wave partial sums of layer-3 dot

    // stage x[:, b] into LDS (one-time)
    for (int n = t; n < T_STEPS; n += 512) x_lds[n] = x[n * BATCH + b];

    // W2 half-column in 32 named float4 registers: rows r0..r0+127, column j
    const float* Wcol = W2 + j;
    #define DECLW(i) float4 w2_##i;
    RPT32(DECLW)
    #define LOADW(i) \
        w2_##i.x = Wcol[(r0 + 4*(i) + 0) * HID]; \
        w2_##i.y = Wcol[(r0 + 4*(i) + 1) * HID]; \
        w2_##i.z = Wcol[(r0 + 4*(i) + 2) * HID]; \
        w2_##i.w = Wcol[(r0 + 4*(i) + 3) * HID];
    RPT32(LOADW)

    const float w1a = W1[j];           // W1[0][j] (state weight)
    const float w1b = W1[HID + j];     // W1[1][j] (input weight)
    const float b1v = b1[j];
    const float b2v = b2[j];
    const float w3v = W3[j];
    const float b3v = b3[0];

    float y = 0.0f;
    __syncthreads();

    for (int n = 0; n < T_STEPS; ++n) {
        // ---- phase A: emit state (idle half), layer 1 (busy half) ----
        if (t == 256) out[n * BATCH + b] = y;   // traj[n] = y_n (pre-update)
        if (t < 256) {
            float xt = x_lds[n];
            float h1 = fast_tanh(fmaf(y, w1a, fmaf(xt, w1b, b1v)));
            h1_lds[j] = h1;
        }
        __syncthreads();

        // ---- phase B: register GEMV partial (half-column dot) ----
        float4 acc; acc.x = 0.f; acc.y = 0.f; acc.z = 0.f; acc.w = 0.f;
        const float4* h4 = ((const float4*)h1_lds) + half * 32;
        #define FMAW(i) { \
            float4 h = h4[i]; /* uniform addr across wave -> LDS broadcast */ \
            acc.x = fmaf(h.x, w2_##i.x, acc.x); \
            acc.y = fmaf(h.y, w2_##i.y, acc.y); \
            acc.z = fmaf(h.z, w2_##i.z, acc.z); \
            acc.w = fmaf(h.w, w2_##i.w, acc.w); }
        RPT32(FMAW)
        part[t] = (acc.x + acc.y) + (acc.z + acc.w);
        __syncthreads();

        // ---- phase C: combine halves, layer-2 tanh, layer-3 dot + reduce ----
        if (t < 256) {
            float q  = part[t] + part[t + 256] + b2v;
            float h2 = fast_tanh(q);
            float p  = h2 * w3v;
            #pragma unroll
            for (int m = 32; m >= 1; m >>= 1) p += __shfl_xor(p, m, 64);
            if (lane == 0) red[wid] = p;
        }
        __syncthreads();

        // all threads update y redundantly (identical fp ops -> identical y)
        y += (red[0] + red[1] + red[2] + red[3]) + b3v;
    }
}

extern "C" void kernel_launch(void* const* d_in, const int* in_sizes, int n_in,
                              void* d_out, int out_size, void* d_ws, size_t ws_size,
                              hipStream_t stream) {
    const float* x  = (const float*)d_in[0];
    const float* W1 = (const float*)d_in[1];
    const float* b1 = (const float*)d_in[2];
    const float* W2 = (const float*)d_in[3];
    const float* b2 = (const float*)d_in[4];
    const float* W3 = (const float*)d_in[5];
    const float* b3 = (const float*)d_in[6];
    float* out = (float*)d_out;

    odenet_kernel<<<dim3(BATCH), dim3(512), 0, stream>>>(x, W1, b1, W2, b2, W3, b3, out);
}